// Round 1
// 317.422 us; speedup vs baseline: 1.3175x; 1.3175x over previous
//
#include <hip/hip_runtime.h>
#include <cmath>

// Problem constants: B=1024, D=2048, P=16384, TEMP=0.05, MOMENTUM=0.2
constexpr int B_N = 1024;
constexpr int D_N = 2048;
constexpr int P_N = 16384;
constexpr int TILE = 128;
constexpr int BK = 64;           // fp8 K-tile (2 MFMA k-steps per buffer)
constexpr int NT = P_N / TILE;   // 128 column tiles
constexpr int NIT = D_N / BK;    // 32 K iterations
#define TEMP_INV 20.0f
#define S_SCALE 16.0f            // storage rows pre-scaled into fp8 range
#define LOGIT_SCALE (TEMP_INV / S_SCALE)
#define MOM 0.2f

typedef __attribute__((ext_vector_type(4))) float floatx4;

__device__ __forceinline__ unsigned int pack4_fp8(float4 v) {
    unsigned int w = __builtin_amdgcn_cvt_pk_fp8_f32(v.x, v.y, 0, false);
    w = __builtin_amdgcn_cvt_pk_fp8_f32(v.z, v.w, w, true);
    return w;
}

__device__ __forceinline__ void gl_lds16(const void* g, void* l) {
    __builtin_amdgcn_global_load_lds(
        (const __attribute__((address_space(1))) void*)g,
        (__attribute__((address_space(3))) void*)l, 16, 0, 0);
}

// ---------------------------------------------------------------------------
// Per-row EMA update-or-copy (sequential duplicate semantics).
// All threads of the block call this uniformly. mask: 16 u64 in LDS,
// red: 4 floats in LDS. v0/v1 = this thread's float4s of S[p].
// ---------------------------------------------------------------------------
__device__ __forceinline__ void row_update(
    const float* __restrict__ X, const int* __restrict__ labels,
    int p, int t, float4 v0, float4 v1, float* __restrict__ outS,
    unsigned long long* mask, float* red) {
    if (t < 16) mask[t] = 0ull;
    __syncthreads();
    for (int u = 0; u < 4; ++u) {
        int k = u * 256 + t;
        if (labels[k] == p) atomicOr(&mask[k >> 6], 1ull << (k & 63));
    }
    __syncthreads();
    unsigned long long any = 0;
    for (int w = 0; w < 16; ++w) any |= mask[w];
    float4* o4 = (float4*)(outS + (size_t)p * D_N);
    if (!any) {  // uniform: plain copy
        o4[t] = v0; o4[256 + t] = v1;
        return;
    }
    float r[8] = {v0.x, v0.y, v0.z, v0.w, v1.x, v1.y, v1.z, v1.w};
    int k = -1;
    for (int w = 0; w < 16; ++w) {
        if (mask[w]) { k = w * 64 + (int)__builtin_ctzll(mask[w]); break; }
    }
    const int lane = t & 63, wv = t >> 6;
    while (k >= 0) {
        const float4* xk = (const float4*)(X + (size_t)k * D_N);
        float4 a0 = xk[t], a1 = xk[256 + t];
        float ss = 0.f;
        r[0] = MOM * r[0] + (1.f - MOM) * a0.x; ss += r[0] * r[0];
        r[1] = MOM * r[1] + (1.f - MOM) * a0.y; ss += r[1] * r[1];
        r[2] = MOM * r[2] + (1.f - MOM) * a0.z; ss += r[2] * r[2];
        r[3] = MOM * r[3] + (1.f - MOM) * a0.w; ss += r[3] * r[3];
        r[4] = MOM * r[4] + (1.f - MOM) * a1.x; ss += r[4] * r[4];
        r[5] = MOM * r[5] + (1.f - MOM) * a1.y; ss += r[5] * r[5];
        r[6] = MOM * r[6] + (1.f - MOM) * a1.z; ss += r[6] * r[6];
        r[7] = MOM * r[7] + (1.f - MOM) * a1.w; ss += r[7] * r[7];
        for (int off = 32; off; off >>= 1) ss += __shfl_xor(ss, off);
        if (lane == 0) red[wv] = ss;
        __syncthreads();
        ss = red[0] + red[1] + red[2] + red[3];
        __syncthreads();
        float inv = 1.0f / sqrtf(ss);
        for (int u = 0; u < 8; ++u) r[u] *= inv;
        // next occurrence (mask is read-only here; uniform across threads)
        int nk = -1;
        int w0 = k >> 6;
        unsigned long long bb = (mask[w0] >> (k & 63)) >> 1;
        if (bb) nk = k + 1 + (int)__builtin_ctzll(bb);
        else {
            for (int w = w0 + 1; w < 16; ++w) {
                if (mask[w]) { nk = w * 64 + (int)__builtin_ctzll(mask[w]); break; }
            }
        }
        k = nk;
    }
    o4[t] = make_float4(r[0], r[1], r[2], r[3]);
    o4[256 + t] = make_float4(r[4], r[5], r[6], r[7]);
}

// ---------------------------------------------------------------------------
// Convert (vectorized: float4 loads, packed u32 fp8 stores) + fused per-row
// EMA-update-or-copy when outS != nullptr. Blocks [0,16384) = S rows,
// [16384,17408) = X rows.
// ---------------------------------------------------------------------------
__global__ __launch_bounds__(256) void convert_update_kernel(
    const float* __restrict__ X, const float* __restrict__ S,
    unsigned char* __restrict__ Xf8, unsigned char* __restrict__ Sf8,
    float* __restrict__ out0, float* __restrict__ outS,
    const int* __restrict__ labels) {
    const int t = threadIdx.x;
    const int p = blockIdx.x;
    if (p == 0 && t == 0) out0[0] = 0.f;
    if (p >= P_N) {  // X conversion
        const int row = p - P_N;
        const float4* x4 = (const float4*)(X + (size_t)row * D_N);
        unsigned int* q = (unsigned int*)(Xf8 + (size_t)row * D_N);
        q[t] = pack4_fp8(x4[t]);
        q[256 + t] = pack4_fp8(x4[256 + t]);
        return;
    }
    const float4* s4 = (const float4*)(S + (size_t)p * D_N);
    unsigned int* q = (unsigned int*)(Sf8 + (size_t)p * D_N);
    float4 v0 = s4[t], v1 = s4[256 + t];
    float4 w0 = make_float4(v0.x * S_SCALE, v0.y * S_SCALE, v0.z * S_SCALE, v0.w * S_SCALE);
    float4 w1 = make_float4(v1.x * S_SCALE, v1.y * S_SCALE, v1.z * S_SCALE, v1.w * S_SCALE);
    q[t] = pack4_fp8(w0);
    q[256 + t] = pack4_fp8(w1);
    if (outS) {
        __shared__ unsigned long long mask[16];
        __shared__ float red[4];
        row_update(X, labels, p, t, v0, v1, outS, mask, red);
    }
}

// ---------------------------------------------------------------------------
// fp8 MFMA GEMM, depth-2 counted-vmcnt pipeline + 16B-chunk XOR swizzle.
//   LDS layout: chunk c of a tile (c=0..511): row = c>>2, physical col = c&3,
//   holding LOGICAL col = (c&3) ^ g(row), g(row) = (row&3)^((row>>2)&3).
//   global_load_lds dest stays linear (base + lane*16); the SOURCE address is
//   pre-swizzled (m173 pattern); reads apply the same XOR.
//   Cuts the ds_read_b64 conflicts 8-way -> 4-way.
// Pipeline: STAGE(t), STAGE(t+1) prologue; per iter: vmcnt(4) [oldest tile
// done, next still in flight] -> barrier -> compute -> barrier -> STAGE(t+2).
// vmcnt(0) only on the last iteration.
// ---------------------------------------------------------------------------
__global__ __launch_bounds__(256, 4) void gemm_softmax_kernel(
    const unsigned char* __restrict__ Xf8, const unsigned char* __restrict__ Sf8,
    float* __restrict__ part_max, float* __restrict__ part_sum) {
    __shared__ alignas(16) unsigned char sA[2][TILE * BK];   // 2 x 8 KB
    __shared__ alignas(16) unsigned char sB[2][TILE * BK];   // 2 x 8 KB
    __shared__ float pmax[2][TILE];
    __shared__ float psum[2][TILE];

    const int t = threadIdx.x;
    // XCD-aware swizzle: each XCD owns 16 contiguous bn tiles (~4MB Sf8 = L2)
    const int b = blockIdx.x;
    const int xcd = b & 7;
    const int s = b >> 3;
    const int bm = s >> 4;                 // 0..7
    const int bn = (xcd << 4) | (s & 15);  // 0..127
    const int m0 = bm * TILE;
    const int n0 = bn * TILE;

    const int lane = t & 63;
    const int wave = t >> 6;
    const int wm = (wave & 1) * 64;
    const int wn = (wave >> 1) * 64;
    const int frow = lane & 15;
    const int q = lane >> 4;               // k-group 0..3 (8 bytes each)

    // ---- staging addresses (source pre-swizzle) ----
    const int r0 = t >> 2, r1 = (t + 256) >> 2;
    const int sc0 = ((t & 3) ^ ((r0 & 3) ^ ((r0 >> 2) & 3))) << 4;
    const int sc1 = ((t & 3) ^ ((r1 & 3) ^ ((r1 >> 2) & 3))) << 4;
    const size_t rowA0 = (size_t)(m0 + r0) * D_N + sc0;
    const size_t rowA1 = (size_t)(m0 + r1) * D_N + sc1;
    const size_t rowB0 = (size_t)(n0 + r0) * D_N + sc0;
    const size_t rowB1 = (size_t)(n0 + r1) * D_N + sc1;

#define STAGE(bi, kt) do { const int kof = (kt) * BK;                 \
        gl_lds16(Xf8 + rowA0 + kof, &sA[bi][t * 16]);                 \
        gl_lds16(Xf8 + rowA1 + kof, &sA[bi][(t + 256) * 16]);         \
        gl_lds16(Sf8 + rowB0 + kof, &sB[bi][t * 16]);                 \
        gl_lds16(Sf8 + rowB1 + kof, &sB[bi][(t + 256) * 16]); } while (0)

    // ---- read offsets (swizzled). Fragment: row r, bytes kk*32 + q*8. ----
    // g(r) = (frow&3)^(frow>>2) since wm+i*16 is a multiple of 16.
    const int gswz = (frow & 3) ^ (frow >> 2);
    const int half = (q & 1) * 8;
    const int l0 = q >> 1;                                // logical col, kk=0
    const int cof0 = (((l0) ^ gswz) << 4) + half;
    const int cof1 = (((l0 | 2) ^ gswz) << 4) + half;     // kk=1: col | 2
    int aoffs[4], boffs[4];
#pragma unroll
    for (int i = 0; i < 4; ++i) aoffs[i] = (wm + i * 16 + frow) * BK;
#pragma unroll
    for (int j = 0; j < 4; ++j) boffs[j] = (wn + j * 16 + frow) * BK;

    floatx4 acc[4][4];
#pragma unroll
    for (int i = 0; i < 4; ++i)
#pragma unroll
        for (int j = 0; j < 4; ++j)
            acc[i][j] = floatx4{0.f, 0.f, 0.f, 0.f};

    STAGE(0, 0);
    STAGE(1, 1);
    int cur = 0;
    for (int it = 0; it < NIT; ++it) {
        if (it < NIT - 1) asm volatile("s_waitcnt vmcnt(4)" ::: "memory");
        else              asm volatile("s_waitcnt vmcnt(0)" ::: "memory");
        __builtin_amdgcn_s_barrier();      // all waves' tile `it` staged
        const unsigned char* pa = &sA[cur][0];
        const unsigned char* pb = &sB[cur][0];
#pragma unroll
        for (int kk = 0; kk < 2; ++kk) {
            const int cof = kk ? cof1 : cof0;
            long long af[4], bf[4];
#pragma unroll
            for (int i = 0; i < 4; ++i)
                af[i] = *(const long long*)(pa + aoffs[i] + cof);
#pragma unroll
            for (int j = 0; j < 4; ++j)
                bf[j] = *(const long long*)(pb + boffs[j] + cof);
#pragma unroll
            for (int i = 0; i < 4; ++i)
#pragma unroll
                for (int j = 0; j < 4; ++j)
                    acc[i][j] = __builtin_amdgcn_mfma_f32_16x16x32_fp8_fp8(
                        af[i], bf[j], acc[i][j], 0, 0, 0);
        }
        __builtin_amdgcn_sched_barrier(0); // pin reads before the barrier
        __builtin_amdgcn_s_barrier();      // all waves done reading buf[cur]
        if (it + 2 < NIT) STAGE(cur, it + 2);
        cur ^= 1;
    }
#undef STAGE

    // Epilogue: per-row max/sumexp over this block's 128 columns.
    // C/D layout: col = lane&15, row = (lane>>4)*4 + reg.
    float lmax[4][4], lsum[4][4];
    for (int i = 0; i < 4; i++) {
        for (int r = 0; r < 4; r++) {
            float m = -INFINITY;
            for (int j = 0; j < 4; j++) m = fmaxf(m, acc[i][j][r] * LOGIT_SCALE);
            for (int off = 1; off < 16; off <<= 1) m = fmaxf(m, __shfl_xor(m, off));
            float s2 = 0.f;
            for (int j = 0; j < 4; j++) s2 += __expf(acc[i][j][r] * LOGIT_SCALE - m);
            for (int off = 1; off < 16; off <<= 1) s2 += __shfl_xor(s2, off);
            lmax[i][r] = m; lsum[i][r] = s2;
        }
    }
    if ((lane & 15) == 0) {
        int lg = lane >> 4;
        for (int i = 0; i < 4; i++)
            for (int r = 0; r < 4; r++) {
                int row = wm + i * 16 + lg * 4 + r;
                pmax[wave >> 1][row] = lmax[i][r];
                psum[wave >> 1][row] = lsum[i][r];
            }
    }
    __syncthreads();
    if (t < TILE) {
        float ma = pmax[0][t], mb = pmax[1][t];
        float M = fmaxf(ma, mb);
        float Sv = psum[0][t] * __expf(ma - M) + psum[1][t] * __expf(mb - M);
        int grow = m0 + t;
        part_max[(size_t)grow * NT + bn] = M;
        part_sum[(size_t)grow * NT + bn] = Sv;
    }
}

// ---------------------------------------------------------------------------
// Loss: one wave per row. Exact fp32 label logit (gather-dot) + LSE over the
// 128 tile partials + mean-NLL atomicAdd into out[0].
// ---------------------------------------------------------------------------
__global__ __launch_bounds__(256) void loss_kernel(
    const float* __restrict__ X, const float* __restrict__ S,
    const int* __restrict__ labels,
    const float* __restrict__ part_max, const float* __restrict__ part_sum,
    float* __restrict__ out0) {
    const int wave = threadIdx.x >> 6, lane = threadIdx.x & 63;
    const int row = blockIdx.x * 4 + wave;
    const float4* x4 = (const float4*)(X + (size_t)row * D_N);
    const float4* s4 = (const float4*)(S + (size_t)labels[row] * D_N);
    float acc = 0.f;
    for (int k = lane; k < D_N / 4; k += 64) {
        float4 a = x4[k], bb = s4[k];
        acc += a.x * bb.x + a.y * bb.y + a.z * bb.z + a.w * bb.w;
    }
    for (int off = 32; off; off >>= 1) acc += __shfl_xor(acc, off);
    float ll = acc * TEMP_INV;
    const float* pm = part_max + (size_t)row * NT;
    const float* ps = part_sum + (size_t)row * NT;
    float m1 = pm[lane], m2 = pm[lane + 64];
    float M = fmaxf(m1, m2);
    for (int off = 32; off; off >>= 1) M = fmaxf(M, __shfl_xor(M, off));
    float Sv = ps[lane] * __expf(m1 - M) + ps[lane + 64] * __expf(m2 - M);
    for (int off = 32; off; off >>= 1) Sv += __shfl_xor(Sv, off);
    float v = ll - (M + __logf(Sv));
    __shared__ float red[4];
    if (lane == 0) red[wave] = v;
    __syncthreads();
    if (threadIdx.x == 0)
        atomicAdd(out0, -(red[0] + red[1] + red[2] + red[3]) * (1.0f / (float)B_N));
}

// Fallback (scratch-in-out path): standalone update-or-copy after loss.
__global__ __launch_bounds__(256) void update_copy_kernel(
    const float* __restrict__ X, const float* __restrict__ S,
    const int* __restrict__ labels, float* __restrict__ outS) {
    __shared__ unsigned long long mask[16];
    __shared__ float red[4];
    const int p = blockIdx.x;
    const int t = threadIdx.x;
    const float4* s4 = (const float4*)(S + (size_t)p * D_N);
    float4 v0 = s4[t], v1 = s4[256 + t];
    row_update(X, labels, p, t, v0, v1, outS, mask, red);
}

extern "C" void kernel_launch(void* const* d_in, const int* in_sizes, int n_in,
                              void* d_out, int out_size, void* d_ws, size_t ws_size,
                              hipStream_t stream) {
    const float* X = (const float*)d_in[0];       // (1024, 2048)
    const float* S = (const float*)d_in[1];       // (16384, 2048)
    const int* labels = (const int*)d_in[4];      // abs_proxy_labels (1024)
    float* out = (float*)d_out;                   // [loss, new_storage...]

    const size_t sf8_bytes = (size_t)P_N * D_N;            // 33,554,432
    const size_t xf8_bytes = (size_t)B_N * D_N;            //  2,097,152
    const size_t need = sf8_bytes + xf8_bytes + (size_t)B_N * NT * 8 + 64;
    const bool use_ws = (ws_size >= need);

    unsigned char* scratch = use_ws ? (unsigned char*)d_ws
                                    : (unsigned char*)d_out + 16;
    unsigned char* Sf8 = scratch;
    unsigned char* Xf8 = scratch + sf8_bytes;
    float* part_max = (float*)(Xf8 + xf8_bytes);
    float* part_sum = part_max + (size_t)B_N * NT;

    // Fused path: convert also performs the EMA-update-or-copy into out+1.
    convert_update_kernel<<<17408, 256, 0, stream>>>(
        X, S, Xf8, Sf8, out, use_ws ? (out + 1) : nullptr, labels);
    gemm_softmax_kernel<<<1024, 256, 0, stream>>>(Xf8, Sf8, part_max, part_sum);
    loss_kernel<<<256, 256, 0, stream>>>(X, S, labels, part_max, part_sum, out);
    if (!use_ws)  // scratch lived inside out: write storage rows now
        update_copy_kernel<<<P_N, 256, 0, stream>>>(X, S, labels, out + 1);
}